// Round 8
// baseline (350.822 us; speedup 1.0000x reference)
//
#include <hip/hip_runtime.h>
#include <cmath>

#define B_ 2
#define N_ 4096
#define E_ 1024
#define D_ 128
#define H_ 8
#define CHUNK 64
#define NC_ (N_/CHUNK)   // 64

__device__ __forceinline__ float sigmoidf_(float x){ return 1.f/(1.f + __expf(-x)); }

__device__ __forceinline__ unsigned short f2bf(float f){
    unsigned u = __float_as_uint(f);
    u += 0x7FFFu + ((u >> 16) & 1u);      // round-to-nearest-even
    return (unsigned short)(u >> 16);
}
__device__ __forceinline__ float bf2f(unsigned short s){
    return __uint_as_float(((unsigned)s) << 16);
}
__device__ __forceinline__ unsigned short f2bf_fast(float f){
    __bf16 h = (__bf16)f;
    return __builtin_bit_cast(unsigned short, h);
}

typedef __attribute__((ext_vector_type(8))) __bf16 bf16x8;
typedef __attribute__((ext_vector_type(4))) float  f32x4;
typedef __attribute__((address_space(3))) unsigned int as3_u32;
typedef __attribute__((address_space(1))) unsigned int as1_u32;

__device__ __forceinline__ void gload_lds16(const void* g, void* l){
    __builtin_amdgcn_global_load_lds((as1_u32*)g, (as3_u32*)l, 16, 0, 0);
}

__device__ __forceinline__ bf16x8 ldsfrag256(const unsigned short* Lp, int row, int kg){
    return *reinterpret_cast<const bf16x8*>(&Lp[row*128 + ((kg ^ (row&7))<<3)]);
}
__device__ __forceinline__ bf16x8 ldsfrag128(const unsigned short* Lp, int row, int kg){
    return *reinterpret_cast<const bf16x8*>(&Lp[row*64 + ((kg ^ (row&7))<<3)]);
}

// ===========================================================================
// 256x256 deep-pipelined bf16 GEMM: C[M,N] = A[M,K] @ Bw[N,K]^T.
// 512 threads = 8 waves (2M x 4N); per-wave out 128x64; BK=64.
// Tile U computed from buf[U&1] in 4 sub-phases (16 MFMA each);
// tile U+1 ds_written from regs into buf[(U+1)&1] during U's phases;
// tile U+2's global loads issued into the other reg set during U's phases.
// One barrier per K-tile. Compiler emits counted vmcnt/lgkmcnt.
// Requires M%256==0, N%256==0, K%128==0.
// ===========================================================================
template<bool OUT_BF16>
__global__ __launch_bounds__(512) void gemm256(
    const unsigned short* __restrict__ Ag,
    const unsigned short* __restrict__ Bg,
    void* __restrict__ Cout, int M, int N, int K)
{
    __shared__ unsigned short As_[2][256*64];
    __shared__ unsigned short Bs_[2][256*64];
    const int tid  = threadIdx.x;
    const int wave = tid >> 6;
    const int lane = tid & 63;
    const int l15 = lane & 15, l4 = lane >> 4;
    const int wm = wave >> 2, wn = wave & 3;

    // XCD-aware bijective swizzle (grid counts are multiples of 8 here)
    const int gx = gridDim.x;
    const int nwg = gx * gridDim.y;
    int bid = blockIdx.y*gx + blockIdx.x;
    bid = (bid & 7)*(nwg >> 3) + (bid >> 3);
    const int m0 = (bid / gx) * 256, n0 = (bid % gx) * 256;

    f32x4 acc[8][4];
#pragma unroll
    for (int i=0;i<8;i++)
#pragma unroll
        for (int j=0;j<4;j++)
#pragma unroll
            for (int q=0;q<4;q++) acc[i][j][q]=0.f;

    bf16x8 a[4][2], b[2][2];
    uint4 s0a[4], s0b[4], s1a[4], s1b[4];

    // ---- prologue: stage tile 0 direct-to-LDS (pre-swizzled source) ----
#pragma unroll
    for (int j=0;j<4;j++){
        const int rbase = wave*32 + j*8;
        const int row = rbase + (lane>>3);
        const int grp = (lane&7) ^ (row&7);
        gload_lds16(Ag + (size_t)(m0+row)*K + grp*8, &As_[0][rbase*64]);
        gload_lds16(Bg + (size_t)(n0+row)*K + grp*8, &Bs_[0][rbase*64]);
    }
    __syncthreads();

#define ISSUE_A(RS, KO) { _Pragma("unroll") \
    for (int i_=0;i_<4;i_++){ const int idx_=i_*512+tid, r_=idx_>>3, g_=idx_&7; \
        RS[i_] = *reinterpret_cast<const uint4*>(Ag + (size_t)(m0+r_)*K + (KO) + g_*8); } }
#define ISSUE_B(RS, KO) { _Pragma("unroll") \
    for (int i_=0;i_<4;i_++){ const int idx_=i_*512+tid, r_=idx_>>3, g_=idx_&7; \
        RS[i_] = *reinterpret_cast<const uint4*>(Bg + (size_t)(n0+r_)*K + (KO) + g_*8); } }
#define WRITE_S(RS, DST) { _Pragma("unroll") \
    for (int i_=0;i_<4;i_++){ const int idx_=i_*512+tid, r_=idx_>>3, g_=idx_&7; \
        *reinterpret_cast<uint4*>(&DST[r_*64 + ((g_ ^ (r_&7))<<3)]) = RS[i_]; } }
#define RD_A(SRC, MQ) { _Pragma("unroll") for (int f_=0;f_<4;f_++) _Pragma("unroll") \
    for (int k_=0;k_<2;k_++) a[f_][k_] = ldsfrag128(SRC, wm*128 + (MQ)*64 + f_*16 + l15, k_*4 + l4); }
#define RD_B(SRC, NQ) { _Pragma("unroll") for (int f_=0;f_<2;f_++) _Pragma("unroll") \
    for (int k_=0;k_<2;k_++) b[f_][k_] = ldsfrag128(SRC, wn*64 + (NQ)*32 + f_*16 + l15, k_*4 + l4); }
#define MM(MQ, NQ) { __builtin_amdgcn_s_setprio(1); _Pragma("unroll") \
    for (int f_=0;f_<4;f_++) _Pragma("unroll") for (int f2_=0;f2_<2;f2_++) _Pragma("unroll") \
    for (int k_=0;k_<2;k_++) acc[(MQ)*4+f_][(NQ)*2+f2_] = __builtin_amdgcn_mfma_f32_16x16x32_bf16( \
        a[f_][k_], b[f2_][k_], acc[(MQ)*4+f_][(NQ)*2+f2_], 0,0,0); __builtin_amdgcn_s_setprio(0); }
#define KITER(CUR, RSWa, RSWb, RSIa, RSIb, KNEXT) { \
    const unsigned short* Ac = As_[CUR]; const unsigned short* Bc = Bs_[CUR]; \
    unsigned short* An = As_[1-(CUR)]; unsigned short* Bn = Bs_[1-(CUR)]; \
    RD_A(Ac, 0); RD_B(Bc, 0); ISSUE_A(RSIa, KNEXT); MM(0,0); \
    RD_B(Bc, 1); ISSUE_B(RSIb, KNEXT); MM(0,1); \
    RD_A(Ac, 1); WRITE_S(RSWa, An); MM(1,1); \
    RD_B(Bc, 0); WRITE_S(RSWb, Bn); MM(1,0); \
    __syncthreads(); }

    const int NT = K >> 6;                  // K-tiles (even; >= 2)
    ISSUE_A(s0a, 64); ISSUE_B(s0b, 64);     // tile 1 -> reg set 0
    for (int U = 0; U < NT; U += 2){
        const int kn1 = (U+2 < NT) ? (U+2)*64 : 0;
        const int kn2 = (U+3 < NT) ? (U+3)*64 : 0;
        KITER(0, s0a, s0b, s1a, s1b, kn1);
        KITER(1, s1a, s1b, s0a, s0b, kn2);
    }
#undef ISSUE_A
#undef ISSUE_B
#undef WRITE_S
#undef RD_A
#undef RD_B
#undef MM
#undef KITER

    const int crow0 = m0 + wm*128 + l4*4;
    const int ccol0 = n0 + wn*64 + l15;
    if (!OUT_BF16){
        float* C = (float*)Cout;
#pragma unroll
        for (int fm=0; fm<8; fm++)
#pragma unroll
            for (int fn=0; fn<4; fn++)
#pragma unroll
                for (int j=0;j<4;j++)
                    C[(size_t)(crow0 + fm*16 + j)*N + ccol0 + fn*16] = acc[fm][fn][j];
    } else {
        unsigned short* C = (unsigned short*)Cout;
#pragma unroll
        for (int fm=0; fm<8; fm++)
#pragma unroll
            for (int fn=0; fn<4; fn++)
#pragma unroll
                for (int j=0;j<4;j++)
                    C[(size_t)(crow0 + fm*16 + j)*N + ccol0 + fn*16] = f2bf(acc[fm][fn][j]);
    }
}

// ---------------------------------------------------------------------------
// 128x128 bf16 MFMA GEMM (m97 structure) — used for the small GEMMs.
// ---------------------------------------------------------------------------
template<bool OUT_BF16>
__global__ __launch_bounds__(256) void gemm_bf16(
    const unsigned short* __restrict__ A,
    const unsigned short* __restrict__ Bw,
    void* __restrict__ Cout, int M, int N, int K)
{
    __shared__ unsigned short As[128*64];
    __shared__ unsigned short Bs[128*64];
    const int tid  = threadIdx.x;
    const int wave = tid >> 6;
    const int lane = tid & 63;
    const int gx = gridDim.x;
    const int nwg = gx * gridDim.y;
    int bid = blockIdx.y*gx + blockIdx.x;
    bid = (bid & 7)*(nwg >> 3) + (bid >> 3);
    const int m0 = (bid / gx) * 128, n0 = (bid % gx) * 128;
    const int wr = (wave >> 1) * 64;
    const int wc = (wave & 1) * 64;
    const int l15 = lane & 15, l4 = lane >> 4;
    const int p = l15 & 7;

    f32x4 acc[4][4];
#pragma unroll
    for (int i=0;i<4;i++)
#pragma unroll
        for (int j=0;j<4;j++)
#pragma unroll
            for (int q=0;q<4;q++) acc[i][j][q]=0.f;

    const int srow = wave*32 + (lane>>3);
    const int sgrp = lane & 7;

    for (int k0=0; k0<K; k0+=64){
        if (k0) __syncthreads();
#pragma unroll
        for (int i=0;i<4;i++){
            const int r  = srow + 8*i;
            const int cg = sgrp ^ (r & 7);
            gload_lds16(A  + (size_t)(m0 + r)*K + k0 + cg*8, &As[(wave*32 + 8*i)*64]);
            gload_lds16(Bw + (size_t)(n0 + r)*K + k0 + cg*8, &Bs[(wave*32 + 8*i)*64]);
        }
        __syncthreads();
#pragma unroll
        for (int ks=0; ks<2; ks++){
            bf16x8 av[4], bv[4];
            const int tA = (((ks<<2) | l4) ^ p) << 3;
#pragma unroll
            for (int f=0; f<4; f++){
                const int rowA = wr + f*16 + l15;
                const int rowB = wc + f*16 + l15;
                av[f] = *reinterpret_cast<const bf16x8*>(&As[(rowA<<6) + tA]);
                bv[f] = *reinterpret_cast<const bf16x8*>(&Bs[(rowB<<6) + tA]);
            }
#pragma unroll
            for (int fm=0; fm<4; fm++)
#pragma unroll
                for (int fn=0; fn<4; fn++)
                    acc[fm][fn] = __builtin_amdgcn_mfma_f32_16x16x32_bf16(
                        av[fm], bv[fn], acc[fm][fn], 0, 0, 0);
        }
    }
    const int crow0 = m0 + wr + l4*4;
    const int ccol0 = n0 + wc + l15;
    if (!OUT_BF16){
        float* C = (float*)Cout;
#pragma unroll
        for (int fm=0; fm<4; fm++)
#pragma unroll
            for (int fn=0; fn<4; fn++)
#pragma unroll
                for (int j=0;j<4;j++)
                    C[(size_t)(crow0 + fm*16 + j)*N + ccol0 + fn*16] = acc[fm][fn][j];
    } else {
        unsigned short* C = (unsigned short*)Cout;
#pragma unroll
        for (int fm=0; fm<4; fm++)
#pragma unroll
            for (int fn=0; fn<4; fn++)
#pragma unroll
                for (int j=0;j<4;j++)
                    C[(size_t)(crow0 + fm*16 + j)*N + ccol0 + fn*16] = f2bf(acc[fm][fn][j]);
    }
}

// ---------------------------------------------------------------------------
// Merged f32 -> bf16 cast for all 5 inputs (one launch).
// ---------------------------------------------------------------------------
#define CQ0 2097152   // x quads
#define CQ1 786432    // W_in
#define CQ2 262144    // W_out
#define CQ3 32768     // W_g1
#define CQ4 32768     // W_g2
__global__ __launch_bounds__(256) void cast_all(
    const float* __restrict__ x,  const float* __restrict__ w1,
    const float* __restrict__ w2, const float* __restrict__ w3,
    const float* __restrict__ w4,
    unsigned short* __restrict__ xb,  unsigned short* __restrict__ w1b,
    unsigned short* __restrict__ w2b, unsigned short* __restrict__ w3b,
    unsigned short* __restrict__ w4b)
{
    const int total = CQ0+CQ1+CQ2+CQ3+CQ4;
    for (int i = blockIdx.x*256 + threadIdx.x; i < total; i += gridDim.x*256){
        const float* src; unsigned short* dst; int off;
        if (i < CQ0){ src=x; dst=xb; off=i; }
        else if (i < CQ0+CQ1){ src=w1; dst=w1b; off=i-CQ0; }
        else if (i < CQ0+CQ1+CQ2){ src=w2; dst=w2b; off=i-CQ0-CQ1; }
        else if (i < CQ0+CQ1+CQ2+CQ3){ src=w3; dst=w3b; off=i-CQ0-CQ1-CQ2; }
        else { src=w4; dst=w4b; off=i-CQ0-CQ1-CQ2-CQ3; }
        const float4 v = reinterpret_cast<const float4*>(src)[off];
        ushort4 o;
        o.x = f2bf(v.x); o.y = f2bf(v.y); o.z = f2bf(v.z); o.w = f2bf(v.w);
        reinterpret_cast<ushort4*>(dst)[off] = o;
    }
}

// ---------------------------------------------------------------------------
// Prep v4 (unchanged from round 7)
// ---------------------------------------------------------------------------
__global__ __launch_bounds__(512) void gla_prep(
    const unsigned short* __restrict__ u, float* __restrict__ EBC,
    unsigned short* __restrict__ QSb, unsigned short* __restrict__ KINb,
    unsigned short* __restrict__ KINtb, unsigned short* __restrict__ Vtb)
{
    __shared__ float tot[4*128];
    const int bid = blockIdx.x;               // (b*H+h)*NC + c
    const int c  = bid % NC_;
    const int hh = (bid / NC_) % H_;
    const int b  = bid / (NC_*H_);
    const int d  = threadIdx.x & 127;
    const int qd = threadIdx.x >> 7;
    const int t0 = qd*16;
    const size_t urow0 = ((size_t)b*N_ + (size_t)c*CHUNK)*(3*E_) + (size_t)hh*D_ + d;

    float bl[16], qv[16], vv[16];
#pragma unroll
    for (int i=0;i<16;i++)
        bl[i] = bf2f(u[urow0 + (size_t)(t0+i)*(3*E_) + 2*E_]);
#pragma unroll
    for (int i=0;i<16;i++)
        qv[i] = bf2f(u[urow0 + (size_t)(t0+i)*(3*E_) + E_]);
#pragma unroll
    for (int i=0;i<16;i++)
        vv[i] = bf2f(u[urow0 + (size_t)(t0+i)*(3*E_)]);

    float acc = 0.f;
#pragma unroll
    for (int i=0;i<16;i++){
        const float lg = bl[i];
        const float e  = __expf(-fabsf(lg));
        const float g  = fminf(lg, 0.f) - __logf(1.f + e);
        acc += g;
        bl[i] = acc;
    }
    tot[qd*128 + d] = acc;
    __syncthreads();
    const float s0 = tot[d], s1 = tot[128+d], s2 = tot[256+d], s3 = tot[384+d];
    const float off = (qd>0 ? s0 : 0.f) + (qd>1 ? s1 : 0.f) + (qd>2 ? s2 : 0.f);
    const float bcv = s0 + s1 + s2 + s3;
    const float ebc = __expf(bcv);
    if (threadIdx.x < 128) EBC[(size_t)bid*D_ + d] = ebc;

    unsigned kin_pk[8], v_pk[8];
    float prev = 0.f;
    const size_t obase = (size_t)bid*CHUNK*D_;
#pragma unroll
    for (int i=0;i<16;i++){
        const int t = t0 + i;
        const float Bl = bl[i];
        const float g  = Bl - prev;  prev = Bl;
        const float Bc = Bl + off;
        const float kk = 1.f - __expf(g);
        const float eB = __expf(Bc);
        const float q  = qv[i];
        const float es = __expf(-q);
        const float silu = q * __builtin_amdgcn_rcpf(1.f + es);
        const float qs  = silu * eB;
        const float kin = kk * __builtin_amdgcn_rcpf(eB);
        QSb [obase + (size_t)t*D_ + d] = f2bf_fast(qs);
        KINb[obase + (size_t)t*D_ + d] = f2bf_fast(kin);
        const unsigned kb = f2bf_fast(kin * ebc);
        const unsigned vb = f2bf_fast(vv[i]);
        if (i & 1){ kin_pk[i>>1] |= kb<<16; v_pk[i>>1] |= vb<<16; }
        else      { kin_pk[i>>1]  = kb;     v_pk[i>>1]  = vb;     }
    }
    const size_t tbase = (size_t)bid*D_*CHUNK + (size_t)d*CHUNK + t0;
#pragma unroll
    for (int j=0;j<2;j++){
        uint4 kq, vq;
        kq.x=kin_pk[4*j]; kq.y=kin_pk[4*j+1]; kq.z=kin_pk[4*j+2]; kq.w=kin_pk[4*j+3];
        vq.x=v_pk[4*j];   vq.y=v_pk[4*j+1];   vq.z=v_pk[4*j+2];   vq.w=v_pk[4*j+3];
        *reinterpret_cast<uint4*>(&KINtb[tbase + j*8]) = kq;
        *reinterpret_cast<uint4*>(&Vtb  [tbase + j*8]) = vq;
    }
}

// ---------------------------------------------------------------------------
__global__ __launch_bounds__(256) void gla_chunk_mm(
    const unsigned short* __restrict__ Vtb,
    const unsigned short* __restrict__ KINtb,
    unsigned short* __restrict__ McTb)
{
    __shared__ unsigned short As[128*64];
    __shared__ unsigned short Bs[128*64];
    const int bid = blockIdx.x;
    const int tid = threadIdx.x;
    const int w = tid >> 6, lane = tid & 63;
    const int l15 = lane & 15, l4 = lane >> 4;
    const int wr = (w >> 1) * 64, wc = (w & 1) * 64;
    const unsigned short* A  = Vtb   + (size_t)bid*128*64;
    const unsigned short* Bp = KINtb + (size_t)bid*128*64;

    f32x4 acc[4][4];
#pragma unroll
    for (int i=0;i<4;i++)
#pragma unroll
        for (int j=0;j<4;j++)
#pragma unroll
            for (int q=0;q<4;q++) acc[i][j][q]=0.f;

#pragma unroll
    for (int i=0;i<4;i++){
        const int r  = w*32 + i*8 + (lane>>3);
        const int gs = (lane&7) ^ (r&7);
        gload_lds16(A  + (size_t)r*64 + gs*8, &As[(w*32+i*8)*64]);
        gload_lds16(Bp + (size_t)r*64 + gs*8, &Bs[(w*32+i*8)*64]);
    }
    __syncthreads();
#pragma unroll
    for (int ks=0; ks<2; ks++){
        bf16x8 av[4], bv[4];
#pragma unroll
        for (int f=0; f<4; f++){
            av[f] = ldsfrag128(As, wr + f*16 + l15, ks*4 + l4);
            bv[f] = ldsfrag128(Bs, wc + f*16 + l15, ks*4 + l4);
        }
#pragma unroll
        for (int fm=0; fm<4; fm++)
#pragma unroll
            for (int fn=0; fn<4; fn++)
                acc[fm][fn] = __builtin_amdgcn_mfma_f32_16x16x32_bf16(
                    av[fm], bv[fn], acc[fm][fn], 0, 0, 0);
    }
    unsigned short* C = McTb + (size_t)bid*128*128;
#pragma unroll
    for (int fm=0; fm<4; fm++)
#pragma unroll
        for (int fn=0; fn<4; fn++)
#pragma unroll
            for (int j=0;j<4;j++)
                C[(size_t)(wr + fm*16 + l4*4 + j)*128 + wc + fn*16 + l15] = f2bf(acc[fm][fn][j]);
}

// ---------------------------------------------------------------------------
__global__ __launch_bounds__(256) void gla_scan_chunks(
    const unsigned short* __restrict__ McTb, const float* __restrict__ EBC,
    unsigned short* __restrict__ Sb16)
{
    const size_t F = (size_t)blockIdx.x*256 + threadIdx.x;   // < B*H*D*D
    const int bh = (int)(F >> 14);
    const int rem = (int)(F & 16383);
    const int d = rem & 127;
    float S = 0.f;
    for (int c=0;c<NC_;c++){
        const size_t idx = (((size_t)bh*NC_ + c) << 14) + rem;
        const float m = bf2f(McTb[idx]);
        const float dec = EBC[((size_t)bh*NC_ + c)*D_ + d];
        Sb16[idx] = f2bf(S);
        S = dec*S + m;
    }
}

// ---------------------------------------------------------------------------
__global__ __launch_bounds__(256) void gla_output(
    const unsigned short* __restrict__ QSb,
    const unsigned short* __restrict__ KINb,
    const unsigned short* __restrict__ Vtb,
    const unsigned short* __restrict__ Sb,
    float* __restrict__ Opre)
{
    __shared__ unsigned short QS_l[64*128];
    __shared__ unsigned short KA_l[64*128];
    __shared__ unsigned short Vt_l[128*64];
    __shared__ unsigned short S_l [128*128];
    const int bid = blockIdx.x;
    const int c = bid % NC_;
    const int h = (bid / NC_) % H_;
    const int b = bid / (NC_*H_);
    const int tid = threadIdx.x;
    const int w = tid >> 6, lane = tid & 63;
    const int l15 = lane & 15, l4 = lane >> 4;

    {
        const unsigned short* q = QSb + (size_t)bid*64*128;
        const unsigned short* k = KINb + (size_t)bid*64*128;
        const unsigned short* v = Vtb + (size_t)bid*128*64;
        const unsigned short* s = Sb  + (size_t)bid*128*128;
#pragma unroll
        for (int i=0;i<4;i++){
            const int r  = w*16 + i*4 + (lane>>4);
            const int gs = (lane&15) ^ (r&7);
            gload_lds16(q + (size_t)r*128 + gs*8, &QS_l[(w*16+i*4)*128]);
            gload_lds16(k + (size_t)r*128 + gs*8, &KA_l[(w*16+i*4)*128]);
        }
#pragma unroll
        for (int i=0;i<4;i++){
            const int r  = w*32 + i*8 + (lane>>3);
            const int gs = (lane&7) ^ (r&7);
            gload_lds16(v + (size_t)r*64 + gs*8, &Vt_l[(w*32+i*8)*64]);
        }
#pragma unroll
        for (int i=0;i<8;i++){
            const int r  = w*32 + i*4 + (lane>>4);
            const int gs = (lane&15) ^ (r&7);
            gload_lds16(s + (size_t)r*128 + gs*8, &S_l[(w*32+i*4)*128]);
        }
    }
    __syncthreads();

    f32x4 accA[4];
#pragma unroll
    for (int i=0;i<4;i++)
#pragma unroll
        for (int q=0;q<4;q++) accA[i][q]=0.f;
    const int srow = w*16 + l15;
#pragma unroll
    for (int ks=0; ks<4; ks++){
        const bf16x8 bv = ldsfrag256(KA_l, srow, ks*4 + l4);
#pragma unroll
        for (int ft=0; ft<4; ft++){
            const bf16x8 av = ldsfrag256(QS_l, ft*16 + l15, ks*4 + l4);
            accA[ft] = __builtin_amdgcn_mfma_f32_16x16x32_bf16(av, bv, accA[ft], 0,0,0);
        }
    }
    __syncthreads();
#pragma unroll
    for (int ft=0; ft<4; ft++)
#pragma unroll
        for (int j=0;j<4;j++){
            const int t = ft*16 + l4*4 + j;
            const int s = w*16 + l15;
            const float vA = (t >= s) ? accA[ft][j] : 0.f;
            KA_l[t*64 + (((s>>3) ^ (t&7))<<3) + (s&7)] = f2bf(vA);
        }
    __syncthreads();

    f32x4 acc[4][2];
#pragma unroll
    for (int i=0;i<4;i++)
#pragma unroll
        for (int j=0;j<2;j++)
#pragma unroll
            for (int q=0;q<4;q++) acc[i][j][q]=0.f;
#pragma unroll
    for (int ks=0; ks<2; ks++){
        bf16x8 bv[2];
        bv[0] = ldsfrag128(Vt_l, w*32 +      l15, ks*4 + l4);
        bv[1] = ldsfrag128(Vt_l, w*32 + 16 + l15, ks*4 + l4);
#pragma unroll
        for (int ft=0; ft<4; ft++){
            const bf16x8 av = ldsfrag128(KA_l, ft*16 + l15, ks*4 + l4);
            acc[ft][0] = __builtin_amdgcn_mfma_f32_16x16x32_bf16(av, bv[0], acc[ft][0], 0,0,0);
            acc[ft][1] = __builtin_amdgcn_mfma_f32_16x16x32_bf16(av, bv[1], acc[ft][1], 0,0,0);
        }
    }
#pragma unroll
    for (int ks=0; ks<4; ks++){
        bf16x8 bv[2];
        bv[0] = ldsfrag256(S_l, w*32 +      l15, ks*4 + l4);
        bv[1] = ldsfrag256(S_l, w*32 + 16 + l15, ks*4 + l4);
#pragma unroll
        for (int ft=0; ft<4; ft++){
            const bf16x8 av = ldsfrag256(QS_l, ft*16 + l15, ks*4 + l4);
            acc[ft][0] = __builtin_amdgcn_mfma_f32_16x16x32_bf16(av, bv[0], acc[ft][0], 0,0,0);
            acc[ft][1] = __builtin_amdgcn_mfma_f32_16x16x32_bf16(av, bv[1], acc[ft][1], 0,0,0);
        }
    }
    const size_t rowbase = (size_t)b*N_ + (size_t)c*CHUNK;
#pragma unroll
    for (int ft=0; ft<4; ft++)
#pragma unroll
        for (int fe=0; fe<2; fe++)
#pragma unroll
            for (int j=0;j<4;j++){
                const int t = ft*16 + l4*4 + j;
                const int e = w*32 + fe*16 + l15;
                Opre[(rowbase + t)*E_ + h*D_ + e] = acc[ft][fe][j];
            }
}

// ---------------------------------------------------------------------------
__global__ __launch_bounds__(256) void gate_ln_bf16(
    const float* __restrict__ O, const unsigned short* __restrict__ G2,
    const float* __restrict__ lnw, unsigned short* __restrict__ Ob)
{
    const int row = blockIdx.x;
    const int tid = threadIdx.x;
    const size_t off = (size_t)row*E_ + tid*4;
    float4 o = *reinterpret_cast<const float4*>(&O[off]);
    const ushort4 gu = *reinterpret_cast<const ushort4*>(&G2[off]);
    o.x *= sigmoidf_(bf2f(gu.x)); o.y *= sigmoidf_(bf2f(gu.y));
    o.z *= sigmoidf_(bf2f(gu.z)); o.w *= sigmoidf_(bf2f(gu.w));
    float s1 = o.x+o.y+o.z+o.w;
    float s2 = o.x*o.x + o.y*o.y + o.z*o.z + o.w*o.w;
#pragma unroll
    for (int sh=32; sh>0; sh>>=1){
        s1 += __shfl_down(s1, sh);
        s2 += __shfl_down(s2, sh);
    }
    __shared__ float r1[4], r2[4];
    const int wid = tid >> 6;
    if ((tid & 63)==0){ r1[wid]=s1; r2[wid]=s2; }
    __syncthreads();
    s1 = r1[0]+r1[1]+r1[2]+r1[3];
    s2 = r2[0]+r2[1]+r2[2]+r2[3];
    const float mean = s1 * (1.f/E_);
    const float var  = s2 * (1.f/E_) - mean*mean;
    const float rs   = rsqrtf(var + 1e-5f);
    const float4 w = *reinterpret_cast<const float4*>(&lnw[tid*4]);
    ushort4 r;
    r.x = f2bf((o.x-mean)*rs*w.x); r.y = f2bf((o.y-mean)*rs*w.y);
    r.z = f2bf((o.z-mean)*rs*w.z); r.w = f2bf((o.w-mean)*rs*w.w);
    *reinterpret_cast<ushort4*>(&Ob[off]) = r;
}

// ---------------------------------------------------------------------------
extern "C" void kernel_launch(void* const* d_in, const int* in_sizes, int n_in,
                              void* d_out, int out_size, void* d_ws, size_t ws_size,
                              hipStream_t stream)
{
    const float* x     = (const float*)d_in[0];
    const float* W_in  = (const float*)d_in[1];
    const float* W_out = (const float*)d_in[2];
    const float* W_g1  = (const float*)d_in[3];
    const float* W_g2  = (const float*)d_in[4];
    const float* lnw   = (const float*)d_in[5];
    float* out = (float*)d_out;
    char* ws = (char*)d_ws;

    // workspace layout (bytes); total 246,415,360 (< 256 MiB)
    unsigned short* ub     = (unsigned short*)(ws);             // [B,N,3E] bf16 (dead after prep); reused:
    unsigned short* McTb   = (unsigned short*)(ws);             //   33,554,432
    unsigned short* Sb16   = (unsigned short*)(ws + 33554432);  //   33,554,432
    float*          EBC    = (float*)(ws + 100663296);          //       524,288
    unsigned short* QSb    = (unsigned short*)(ws + 101187584); //    16,777,216
    unsigned short* KINb   = (unsigned short*)(ws + 117964800); //    16,777,216
    unsigned short* KINtb  = (unsigned short*)(ws + 134742016); //    16,777,216
    unsigned short* Vtb    = (unsigned short*)(ws + 151519232); //    16,777,216
    float*          Opre   = (float*)(ws + 168296448);          //    33,554,432
    unsigned short* xb     = (unsigned short*)(ws + 201850880); //    16,777,216
    unsigned short* W_inb  = (unsigned short*)(ws + 218628096); //     6,291,456
    unsigned short* W_outb = (unsigned short*)(ws + 224919552); //     2,097,152
    unsigned short* W_g1b  = (unsigned short*)(ws + 227016704); //       262,144
    unsigned short* W_g2b  = (unsigned short*)(ws + 227278848); //       262,144
    unsigned short* G1b    = (unsigned short*)(ws + 227540992); //     2,097,152
    unsigned short* ObF    = (unsigned short*)(ws + 229638144); //    16,777,216
    unsigned short* G2b    = QSb;   // reuse QSb (dead after gla_output)

    const int M = B_*N_;     // 8192
    dim3 blk(256);

    // one merged cast launch
    cast_all<<<2048, blk, 0, stream>>>(x, W_in, W_out, W_g1, W_g2,
                                       xb, W_inb, W_outb, W_g1b, W_g2b);

    // 1) u = x @ W_in^T  (bf16 out) — 256^2 deep-pipelined
    gemm256<true><<<dim3(3*E_/256, M/256), dim3(512), 0, stream>>>(xb, W_inb, ub, M, 3*E_, E_);
    // 2) prep
    gla_prep<<<dim3(B_*H_*NC_), dim3(512), 0, stream>>>(ub, EBC, QSb, KINb, KINtb, Vtb);
    // 3) per-chunk summaries
    gla_chunk_mm<<<dim3(B_*H_*NC_), blk, 0, stream>>>(Vtb, KINtb, McTb);
    // 4) inter-chunk scan
    gla_scan_chunks<<<dim3((B_*H_*D_*D_)/256), blk, 0, stream>>>(McTb, EBC, Sb16);
    // 5) per-chunk outputs
    gla_output<<<dim3(B_*H_*NC_), blk, 0, stream>>>(QSb, KINb, Vtb, Sb16, Opre);
    // 6) G1 = x @ W_g1^T  (bf16 out)
    gemm_bf16<true><<<dim3(1, M/128), blk, 0, stream>>>(xb, W_g1b, G1b, M, D_, E_);
    // 7) G2 = G1 @ W_g2^T (bf16 out, over dead QSb)
    gemm_bf16<true><<<dim3(E_/128, M/128), blk, 0, stream>>>(G1b, W_g2b, G2b, M, E_, D_);
    // 8) gate + layernorm -> bf16
    gate_ln_bf16<<<dim3(M), blk, 0, stream>>>(Opre, G2b, lnw, ObF);
    // 9) out = LN(o) @ W_out^T — 256^2 deep-pipelined
    gemm256<false><<<dim3(E_/256, M/256), dim3(512), 0, stream>>>(ObF, W_outb, out, M, E_, E_);
}

// Round 9
// 215.323 us; speedup vs baseline: 1.6293x; 1.6293x over previous
//
#include <hip/hip_runtime.h>
#include <cmath>

#define B_ 2
#define N_ 4096
#define E_ 1024
#define D_ 128
#define H_ 8
#define CHUNK 64
#define NC_ (N_/CHUNK)   // 64

__device__ __forceinline__ float sigmoidf_(float x){ return 1.f/(1.f + __expf(-x)); }

__device__ __forceinline__ unsigned short f2bf(float f){
    unsigned u = __float_as_uint(f);
    u += 0x7FFFu + ((u >> 16) & 1u);      // round-to-nearest-even
    return (unsigned short)(u >> 16);
}
__device__ __forceinline__ float bf2f(unsigned short s){
    return __uint_as_float(((unsigned)s) << 16);
}
__device__ __forceinline__ unsigned short f2bf_fast(float f){
    __bf16 h = (__bf16)f;
    return __builtin_bit_cast(unsigned short, h);
}

typedef __attribute__((ext_vector_type(8))) __bf16 bf16x8;
typedef __attribute__((ext_vector_type(4))) float  f32x4;
typedef __attribute__((address_space(3))) unsigned int as3_u32;
typedef __attribute__((address_space(1))) unsigned int as1_u32;

__device__ __forceinline__ void gload_lds16(const void* g, void* l){
    __builtin_amdgcn_global_load_lds((as1_u32*)g, (as3_u32*)l, 16, 0, 0);
}

__device__ __forceinline__ bf16x8 ldsfrag256(const unsigned short* Lp, int row, int kg){
    return *reinterpret_cast<const bf16x8*>(&Lp[row*128 + ((kg ^ (row&7))<<3)]);
}
__device__ __forceinline__ bf16x8 ldsfrag128(const unsigned short* Lp, int row, int kg){
    return *reinterpret_cast<const bf16x8*>(&Lp[row*64 + ((kg ^ (row&7))<<3)]);
}

// ===========================================================================
// Pipelined bf16 GEMM, 128(M) x 256(N) tile, BK=64, 512 threads = 8 waves
// (2M x 4N), per-wave 64x64 output. global_load_lds staging (no staging
// VGPRs), THREE LDS buffers (144 KB): compute tile t from buf[t%3] while
// tile t+2's loads land in buf[(t+2)%3] (freed by tile t-1). Boundary uses
// counted s_waitcnt vmcnt(6) + raw s_barrier — never a full drain in the
// main loop (T4). Requires M%128==0, N%256==0, K%64==0, K/64 >= 2.
// ===========================================================================
template<bool OUT_BF16>
__global__ __launch_bounds__(512) void gemm_pipe(
    const unsigned short* __restrict__ Ag,
    const unsigned short* __restrict__ Bg,
    void* __restrict__ Cout, int M, int N, int K)
{
    __shared__ unsigned short LDS[73728];   // 3 x (A[128][64] + B[256][64]) = 144 KB
    const int tid  = threadIdx.x;
    const int wave = tid >> 6;
    const int lane = tid & 63;
    const int l15 = lane & 15, l4 = lane >> 4;
    const int wm = wave >> 2, wn = wave & 3;     // 2 x 4 wave grid

    // XCD-aware bijective swizzle (nwg % 8 == 0 for all launches here)
    const int gx = gridDim.x;                    // N/256
    const int nwg = gx * gridDim.y;
    int bid = blockIdx.y*gx + blockIdx.x;
    bid = (bid & 7)*(nwg >> 3) + (bid >> 3);
    const int m0 = (bid / gx) * 128, n0 = (bid % gx) * 256;

    f32x4 acc[4][4];
#pragma unroll
    for (int i=0;i<4;i++)
#pragma unroll
        for (int j=0;j<4;j++)
#pragma unroll
            for (int q=0;q<4;q++) acc[i][j][q]=0.f;

    const int rs  = wave*8 + (lane>>3);          // staging row within 64-row slab
    const int cg0 = lane & 7;                    // 16B col-group

    auto STAGE = [&](int kt, int bufi){          // 6 gloads/thread: 2 A + 4 B
        unsigned short* Ab = &LDS[bufi*24576];
        unsigned short* Bb = &LDS[bufi*24576 + 8192];
        const int k0 = kt*64;
#pragma unroll
        for (int i=0;i<2;i++){
            const int row = i*64 + rs;
            gload_lds16(Ag + (size_t)(m0+row)*K + k0 + ((cg0 ^ (row&7))<<3),
                        &Ab[(i*64 + wave*8)*64]);
        }
#pragma unroll
        for (int i=0;i<4;i++){
            const int row = i*64 + rs;
            gload_lds16(Bg + (size_t)(n0+row)*K + k0 + ((cg0 ^ (row&7))<<3),
                        &Bb[(i*64 + wave*8)*64]);
        }
    };

    auto COMPUTE = [&](int bufi){
        const unsigned short* Ab = &LDS[bufi*24576];
        const unsigned short* Bb = &LDS[bufi*24576 + 8192];
#pragma unroll
        for (int ks=0; ks<2; ks++){
            bf16x8 a[4], b[4];
#pragma unroll
            for (int f=0; f<4; f++) a[f] = ldsfrag128(Ab, wm*64 + f*16 + l15, ks*4 + l4);
#pragma unroll
            for (int f=0; f<4; f++) b[f] = ldsfrag128(Bb, wn*64 + f*16 + l15, ks*4 + l4);
            __builtin_amdgcn_s_setprio(1);
#pragma unroll
            for (int fm=0; fm<4; fm++)
#pragma unroll
                for (int fn=0; fn<4; fn++)
                    acc[fm][fn] = __builtin_amdgcn_mfma_f32_16x16x32_bf16(
                        a[fm], b[fn], acc[fm][fn], 0, 0, 0);
            __builtin_amdgcn_s_setprio(0);
        }
    };

    const int NT = K >> 6;                       // >= 2
    STAGE(0, 0);
    STAGE(1, 1);
    asm volatile("s_waitcnt vmcnt(6)" ::: "memory");   // tile 0 landed
    __builtin_amdgcn_s_barrier();
    __builtin_amdgcn_sched_barrier(0);

    int bc = 0, bn2 = 2;
    for (int t=0; t<NT; ++t){
        if (t+2 < NT) STAGE(t+2, bn2);           // into buffer freed by tile t-1
        COMPUTE(bc);
        if (t+1 < NT){
            if (t+2 < NT){ asm volatile("s_waitcnt vmcnt(6)" ::: "memory"); }
            else         { asm volatile("s_waitcnt vmcnt(0)" ::: "memory"); }
            __builtin_amdgcn_s_barrier();
            __builtin_amdgcn_sched_barrier(0);
        }
        bc  = (bc  == 2) ? 0 : bc  + 1;
        bn2 = (bn2 == 2) ? 0 : bn2 + 1;
    }

    const int crow0 = m0 + wm*64 + l4*4;
    const int ccol0 = n0 + wn*64 + l15;
    if (!OUT_BF16){
        float* C = (float*)Cout;
#pragma unroll
        for (int fm=0; fm<4; fm++)
#pragma unroll
            for (int fn=0; fn<4; fn++)
#pragma unroll
                for (int j=0;j<4;j++)
                    C[(size_t)(crow0 + fm*16 + j)*N + ccol0 + fn*16] = acc[fm][fn][j];
    } else {
        unsigned short* C = (unsigned short*)Cout;
#pragma unroll
        for (int fm=0; fm<4; fm++)
#pragma unroll
            for (int fn=0; fn<4; fn++)
#pragma unroll
                for (int j=0;j<4;j++)
                    C[(size_t)(crow0 + fm*16 + j)*N + ccol0 + fn*16] = f2bf(acc[fm][fn][j]);
    }
}

// ---------------------------------------------------------------------------
// 128x128 bf16 MFMA GEMM (m97 structure) — used for the small GEMMs.
// ---------------------------------------------------------------------------
template<bool OUT_BF16>
__global__ __launch_bounds__(256) void gemm_bf16(
    const unsigned short* __restrict__ A,
    const unsigned short* __restrict__ Bw,
    void* __restrict__ Cout, int M, int N, int K)
{
    __shared__ unsigned short As[128*64];
    __shared__ unsigned short Bs[128*64];
    const int tid  = threadIdx.x;
    const int wave = tid >> 6;
    const int lane = tid & 63;
    const int gx = gridDim.x;
    const int nwg = gx * gridDim.y;
    int bid = blockIdx.y*gx + blockIdx.x;
    bid = (bid & 7)*(nwg >> 3) + (bid >> 3);
    const int m0 = (bid / gx) * 128, n0 = (bid % gx) * 128;
    const int wr = (wave >> 1) * 64;
    const int wc = (wave & 1) * 64;
    const int l15 = lane & 15, l4 = lane >> 4;
    const int p = l15 & 7;

    f32x4 acc[4][4];
#pragma unroll
    for (int i=0;i<4;i++)
#pragma unroll
        for (int j=0;j<4;j++)
#pragma unroll
            for (int q=0;q<4;q++) acc[i][j][q]=0.f;

    const int srow = wave*32 + (lane>>3);
    const int sgrp = lane & 7;

    for (int k0=0; k0<K; k0+=64){
        if (k0) __syncthreads();
#pragma unroll
        for (int i=0;i<4;i++){
            const int r  = srow + 8*i;
            const int cg = sgrp ^ (r & 7);
            gload_lds16(A  + (size_t)(m0 + r)*K + k0 + cg*8, &As[(wave*32 + 8*i)*64]);
            gload_lds16(Bw + (size_t)(n0 + r)*K + k0 + cg*8, &Bs[(wave*32 + 8*i)*64]);
        }
        __syncthreads();
#pragma unroll
        for (int ks=0; ks<2; ks++){
            bf16x8 av[4], bv[4];
            const int tA = (((ks<<2) | l4) ^ p) << 3;
#pragma unroll
            for (int f=0; f<4; f++){
                const int rowA = wr + f*16 + l15;
                const int rowB = wc + f*16 + l15;
                av[f] = *reinterpret_cast<const bf16x8*>(&As[(rowA<<6) + tA]);
                bv[f] = *reinterpret_cast<const bf16x8*>(&Bs[(rowB<<6) + tA]);
            }
#pragma unroll
            for (int fm=0; fm<4; fm++)
#pragma unroll
                for (int fn=0; fn<4; fn++)
                    acc[fm][fn] = __builtin_amdgcn_mfma_f32_16x16x32_bf16(
                        av[fm], bv[fn], acc[fm][fn], 0, 0, 0);
        }
    }
    const int crow0 = m0 + wr + l4*4;
    const int ccol0 = n0 + wc + l15;
    if (!OUT_BF16){
        float* C = (float*)Cout;
#pragma unroll
        for (int fm=0; fm<4; fm++)
#pragma unroll
            for (int fn=0; fn<4; fn++)
#pragma unroll
                for (int j=0;j<4;j++)
                    C[(size_t)(crow0 + fm*16 + j)*N + ccol0 + fn*16] = acc[fm][fn][j];
    } else {
        unsigned short* C = (unsigned short*)Cout;
#pragma unroll
        for (int fm=0; fm<4; fm++)
#pragma unroll
            for (int fn=0; fn<4; fn++)
#pragma unroll
                for (int j=0;j<4;j++)
                    C[(size_t)(crow0 + fm*16 + j)*N + ccol0 + fn*16] = f2bf(acc[fm][fn][j]);
    }
}

// ---------------------------------------------------------------------------
// Merged f32 -> bf16 cast for all 5 inputs (one launch).
// ---------------------------------------------------------------------------
#define CQ0 2097152   // x quads
#define CQ1 786432    // W_in
#define CQ2 262144    // W_out
#define CQ3 32768     // W_g1
#define CQ4 32768     // W_g2
__global__ __launch_bounds__(256) void cast_all(
    const float* __restrict__ x,  const float* __restrict__ w1,
    const float* __restrict__ w2, const float* __restrict__ w3,
    const float* __restrict__ w4,
    unsigned short* __restrict__ xb,  unsigned short* __restrict__ w1b,
    unsigned short* __restrict__ w2b, unsigned short* __restrict__ w3b,
    unsigned short* __restrict__ w4b)
{
    const int total = CQ0+CQ1+CQ2+CQ3+CQ4;
    for (int i = blockIdx.x*256 + threadIdx.x; i < total; i += gridDim.x*256){
        const float* src; unsigned short* dst; int off;
        if (i < CQ0){ src=x; dst=xb; off=i; }
        else if (i < CQ0+CQ1){ src=w1; dst=w1b; off=i-CQ0; }
        else if (i < CQ0+CQ1+CQ2){ src=w2; dst=w2b; off=i-CQ0-CQ1; }
        else if (i < CQ0+CQ1+CQ2+CQ3){ src=w3; dst=w3b; off=i-CQ0-CQ1-CQ2; }
        else { src=w4; dst=w4b; off=i-CQ0-CQ1-CQ2-CQ3; }
        const float4 v = reinterpret_cast<const float4*>(src)[off];
        ushort4 o;
        o.x = f2bf(v.x); o.y = f2bf(v.y); o.z = f2bf(v.z); o.w = f2bf(v.w);
        reinterpret_cast<ushort4*>(dst)[off] = o;
    }
}

// ---------------------------------------------------------------------------
// Prep v4 (unchanged)
// ---------------------------------------------------------------------------
__global__ __launch_bounds__(512) void gla_prep(
    const unsigned short* __restrict__ u, float* __restrict__ EBC,
    unsigned short* __restrict__ QSb, unsigned short* __restrict__ KINb,
    unsigned short* __restrict__ KINtb, unsigned short* __restrict__ Vtb)
{
    __shared__ float tot[4*128];
    const int bid = blockIdx.x;               // (b*H+h)*NC + c
    const int c  = bid % NC_;
    const int hh = (bid / NC_) % H_;
    const int b  = bid / (NC_*H_);
    const int d  = threadIdx.x & 127;
    const int qd = threadIdx.x >> 7;
    const int t0 = qd*16;
    const size_t urow0 = ((size_t)b*N_ + (size_t)c*CHUNK)*(3*E_) + (size_t)hh*D_ + d;

    float bl[16], qv[16], vv[16];
#pragma unroll
    for (int i=0;i<16;i++)
        bl[i] = bf2f(u[urow0 + (size_t)(t0+i)*(3*E_) + 2*E_]);
#pragma unroll
    for (int i=0;i<16;i++)
        qv[i] = bf2f(u[urow0 + (size_t)(t0+i)*(3*E_) + E_]);
#pragma unroll
    for (int i=0;i<16;i++)
        vv[i] = bf2f(u[urow0 + (size_t)(t0+i)*(3*E_)]);

    float acc = 0.f;
#pragma unroll
    for (int i=0;i<16;i++){
        const float lg = bl[i];
        const float e  = __expf(-fabsf(lg));
        const float g  = fminf(lg, 0.f) - __logf(1.f + e);
        acc += g;
        bl[i] = acc;
    }
    tot[qd*128 + d] = acc;
    __syncthreads();
    const float s0 = tot[d], s1 = tot[128+d], s2 = tot[256+d], s3 = tot[384+d];
    const float off = (qd>0 ? s0 : 0.f) + (qd>1 ? s1 : 0.f) + (qd>2 ? s2 : 0.f);
    const float bcv = s0 + s1 + s2 + s3;
    const float ebc = __expf(bcv);
    if (threadIdx.x < 128) EBC[(size_t)bid*D_ + d] = ebc;

    unsigned kin_pk[8], v_pk[8];
    float prev = 0.f;
    const size_t obase = (size_t)bid*CHUNK*D_;
#pragma unroll
    for (int i=0;i<16;i++){
        const int t = t0 + i;
        const float Bl = bl[i];
        const float g  = Bl - prev;  prev = Bl;
        const float Bc = Bl + off;
        const float kk = 1.f - __expf(g);
        const float eB = __expf(Bc);
        const float q  = qv[i];
        const float es = __expf(-q);
        const float silu = q * __builtin_amdgcn_rcpf(1.f + es);
        const float qs  = silu * eB;
        const float kin = kk * __builtin_amdgcn_rcpf(eB);
        QSb [obase + (size_t)t*D_ + d] = f2bf_fast(qs);
        KINb[obase + (size_t)t*D_ + d] = f2bf_fast(kin);
        const unsigned kb = f2bf_fast(kin * ebc);
        const unsigned vb = f2bf_fast(vv[i]);
        if (i & 1){ kin_pk[i>>1] |= kb<<16; v_pk[i>>1] |= vb<<16; }
        else      { kin_pk[i>>1]  = kb;     v_pk[i>>1]  = vb;     }
    }
    const size_t tbase = (size_t)bid*D_*CHUNK + (size_t)d*CHUNK + t0;
#pragma unroll
    for (int j=0;j<2;j++){
        uint4 kq, vq;
        kq.x=kin_pk[4*j]; kq.y=kin_pk[4*j+1]; kq.z=kin_pk[4*j+2]; kq.w=kin_pk[4*j+3];
        vq.x=v_pk[4*j];   vq.y=v_pk[4*j+1];   vq.z=v_pk[4*j+2];   vq.w=v_pk[4*j+3];
        *reinterpret_cast<uint4*>(&KINtb[tbase + j*8]) = kq;
        *reinterpret_cast<uint4*>(&Vtb  [tbase + j*8]) = vq;
    }
}

// ---------------------------------------------------------------------------
__global__ __launch_bounds__(256) void gla_chunk_mm(
    const unsigned short* __restrict__ Vtb,
    const unsigned short* __restrict__ KINtb,
    unsigned short* __restrict__ McTb)
{
    __shared__ unsigned short As[128*64];
    __shared__ unsigned short Bs[128*64];
    const int bid = blockIdx.x;
    const int tid = threadIdx.x;
    const int w = tid >> 6, lane = tid & 63;
    const int l15 = lane & 15, l4 = lane >> 4;
    const int wr = (w >> 1) * 64, wc = (w & 1) * 64;
    const unsigned short* A  = Vtb   + (size_t)bid*128*64;
    const unsigned short* Bp = KINtb + (size_t)bid*128*64;

    f32x4 acc[4][4];
#pragma unroll
    for (int i=0;i<4;i++)
#pragma unroll
        for (int j=0;j<4;j++)
#pragma unroll
            for (int q=0;q<4;q++) acc[i][j][q]=0.f;

#pragma unroll
    for (int i=0;i<4;i++){
        const int r  = w*32 + i*8 + (lane>>3);
        const int gs = (lane&7) ^ (r&7);
        gload_lds16(A  + (size_t)r*64 + gs*8, &As[(w*32+i*8)*64]);
        gload_lds16(Bp + (size_t)r*64 + gs*8, &Bs[(w*32+i*8)*64]);
    }
    __syncthreads();
#pragma unroll
    for (int ks=0; ks<2; ks++){
        bf16x8 av[4], bv[4];
#pragma unroll
        for (int f=0; f<4; f++){
            av[f] = ldsfrag128(As, wr + f*16 + l15, ks*4 + l4);
            bv[f] = ldsfrag128(Bs, wc + f*16 + l15, ks*4 + l4);
        }
#pragma unroll
        for (int fm=0; fm<4; fm++)
#pragma unroll
            for (int fn=0; fn<4; fn++)
                acc[fm][fn] = __builtin_amdgcn_mfma_f32_16x16x32_bf16(
                    av[fm], bv[fn], acc[fm][fn], 0, 0, 0);
    }
    unsigned short* C = McTb + (size_t)bid*128*128;
#pragma unroll
    for (int fm=0; fm<4; fm++)
#pragma unroll
        for (int fn=0; fn<4; fn++)
#pragma unroll
            for (int j=0;j<4;j++)
                C[(size_t)(wr + fm*16 + l4*4 + j)*128 + wc + fn*16 + l15] = f2bf(acc[fm][fn][j]);
}

// ---------------------------------------------------------------------------
__global__ __launch_bounds__(256) void gla_scan_chunks(
    const unsigned short* __restrict__ McTb, const float* __restrict__ EBC,
    unsigned short* __restrict__ Sb16)
{
    const size_t F = (size_t)blockIdx.x*256 + threadIdx.x;   // < B*H*D*D
    const int bh = (int)(F >> 14);
    const int rem = (int)(F & 16383);
    const int d = rem & 127;
    float S = 0.f;
    for (int c=0;c<NC_;c++){
        const size_t idx = (((size_t)bh*NC_ + c) << 14) + rem;
        const float m = bf2f(McTb[idx]);
        const float dec = EBC[((size_t)bh*NC_ + c)*D_ + d];
        Sb16[idx] = f2bf(S);
        S = dec*S + m;
    }
}

// ---------------------------------------------------------------------------
__global__ __launch_bounds__(256) void gla_output(
    const unsigned short* __restrict__ QSb,
    const unsigned short* __restrict__ KINb,
    const unsigned short* __restrict__ Vtb,
    const unsigned short* __restrict__ Sb,
    float* __restrict__ Opre)
{
    __shared__ unsigned short QS_l[64*128];
    __shared__ unsigned short KA_l[64*128];
    __shared__ unsigned short Vt_l[128*64];
    __shared__ unsigned short S_l [128*128];
    const int bid = blockIdx.x;
    const int c = bid % NC_;
    const int h = (bid / NC_) % H_;
    const int b = bid / (NC_*H_);
    const int tid = threadIdx.x;
    const int w = tid >> 6, lane = tid & 63;
    const int l15 = lane & 15, l4 = lane >> 4;

    {
        const unsigned short* q = QSb + (size_t)bid*64*128;
        const unsigned short* k = KINb + (size_t)bid*64*128;
        const unsigned short* v = Vtb + (size_t)bid*128*64;
        const unsigned short* s = Sb  + (size_t)bid*128*128;
#pragma unroll
        for (int i=0;i<4;i++){
            const int r  = w*16 + i*4 + (lane>>4);
            const int gs = (lane&15) ^ (r&7);
            gload_lds16(q + (size_t)r*128 + gs*8, &QS_l[(w*16+i*4)*128]);
            gload_lds16(k + (size_t)r*128 + gs*8, &KA_l[(w*16+i*4)*128]);
        }
#pragma unroll
        for (int i=0;i<4;i++){
            const int r  = w*32 + i*8 + (lane>>3);
            const int gs = (lane&7) ^ (r&7);
            gload_lds16(v + (size_t)r*64 + gs*8, &Vt_l[(w*32+i*8)*64]);
        }
#pragma unroll
        for (int i=0;i<8;i++){
            const int r  = w*32 + i*4 + (lane>>4);
            const int gs = (lane&15) ^ (r&7);
            gload_lds16(s + (size_t)r*128 + gs*8, &S_l[(w*32+i*4)*128]);
        }
    }
    __syncthreads();

    f32x4 accA[4];
#pragma unroll
    for (int i=0;i<4;i++)
#pragma unroll
        for (int q=0;q<4;q++) accA[i][q]=0.f;
    const int srow = w*16 + l15;
#pragma unroll
    for (int ks=0; ks<4; ks++){
        const bf16x8 bv = ldsfrag256(KA_l, srow, ks*4 + l4);
#pragma unroll
        for (int ft=0; ft<4; ft++){
            const bf16x8 av = ldsfrag256(QS_l, ft*16 + l15, ks*4 + l4);
            accA[ft] = __builtin_amdgcn_mfma_f32_16x16x32_bf16(av, bv, accA[ft], 0,0,0);
        }
    }
    __syncthreads();
#pragma unroll
    for (int ft=0; ft<4; ft++)
#pragma unroll
        for (int j=0;j<4;j++){
            const int t = ft*16 + l4*4 + j;
            const int s = w*16 + l15;
            const float vA = (t >= s) ? accA[ft][j] : 0.f;
            KA_l[t*64 + (((s>>3) ^ (t&7))<<3) + (s&7)] = f2bf(vA);
        }
    __syncthreads();

    f32x4 acc[4][2];
#pragma unroll
    for (int i=0;i<4;i++)
#pragma unroll
        for (int j=0;j<2;j++)
#pragma unroll
            for (int q=0;q<4;q++) acc[i][j][q]=0.f;
#pragma unroll
    for (int ks=0; ks<2; ks++){
        bf16x8 bv[2];
        bv[0] = ldsfrag128(Vt_l, w*32 +      l15, ks*4 + l4);
        bv[1] = ldsfrag128(Vt_l, w*32 + 16 + l15, ks*4 + l4);
#pragma unroll
        for (int ft=0; ft<4; ft++){
            const bf16x8 av = ldsfrag128(KA_l, ft*16 + l15, ks*4 + l4);
            acc[ft][0] = __builtin_amdgcn_mfma_f32_16x16x32_bf16(av, bv[0], acc[ft][0], 0,0,0);
            acc[ft][1] = __builtin_amdgcn_mfma_f32_16x16x32_bf16(av, bv[1], acc[ft][1], 0,0,0);
        }
    }
#pragma unroll
    for (int ks=0; ks<4; ks++){
        bf16x8 bv[2];
        bv[0] = ldsfrag256(S_l, w*32 +      l15, ks*4 + l4);
        bv[1] = ldsfrag256(S_l, w*32 + 16 + l15, ks*4 + l4);
#pragma unroll
        for (int ft=0; ft<4; ft++){
            const bf16x8 av = ldsfrag256(QS_l, ft*16 + l15, ks*4 + l4);
            acc[ft][0] = __builtin_amdgcn_mfma_f32_16x16x32_bf16(av, bv[0], acc[ft][0], 0,0,0);
            acc[ft][1] = __builtin_amdgcn_mfma_f32_16x16x32_bf16(av, bv[1], acc[ft][1], 0,0,0);
        }
    }
    const size_t rowbase = (size_t)b*N_ + (size_t)c*CHUNK;
#pragma unroll
    for (int ft=0; ft<4; ft++)
#pragma unroll
        for (int fe=0; fe<2; fe++)
#pragma unroll
            for (int j=0;j<4;j++){
                const int t = ft*16 + l4*4 + j;
                const int e = w*32 + fe*16 + l15;
                Opre[(rowbase + t)*E_ + h*D_ + e] = acc[ft][fe][j];
            }
}

// ---------------------------------------------------------------------------
__global__ __launch_bounds__(256) void gate_ln_bf16(
    const float* __restrict__ O, const unsigned short* __restrict__ G2,
    const float* __restrict__ lnw, unsigned short* __restrict__ Ob)
{
    const int row = blockIdx.x;
    const int tid = threadIdx.x;
    const size_t off = (size_t)row*E_ + tid*4;
    float4 o = *reinterpret_cast<const float4*>(&O[off]);
    const ushort4 gu = *reinterpret_cast<const ushort4*>(&G2[off]);
    o.x *= sigmoidf_(bf2f(gu.x)); o.y *= sigmoidf_(bf2f(gu.y));
    o.z *= sigmoidf_(bf2f(gu.z)); o.w *= sigmoidf_(bf2f(gu.w));
    float s1 = o.x+o.y+o.z+o.w;
    float s2 = o.x*o.x + o.y*o.y + o.z*o.z + o.w*o.w;
#pragma unroll
    for (int sh=32; sh>0; sh>>=1){
        s1 += __shfl_down(s1, sh);
        s2 += __shfl_down(s2, sh);
    }
    __shared__ float r1[4], r2[4];
    const int wid = tid >> 6;
    if ((tid & 63)==0){ r1[wid]=s1; r2[wid]=s2; }
    __syncthreads();
    s1 = r1[0]+r1[1]+r1[2]+r1[3];
    s2 = r2[0]+r2[1]+r2[2]+r2[3];
    const float mean = s1 * (1.f/E_);
    const float var  = s2 * (1.f/E_) - mean*mean;
    const float rs   = rsqrtf(var + 1e-5f);
    const float4 w = *reinterpret_cast<const float4*>(&lnw[tid*4]);
    ushort4 r;
    r.x = f2bf((o.x-mean)*rs*w.x); r.y = f2bf((o.y-mean)*rs*w.y);
    r.z = f2bf((o.z-mean)*rs*w.z); r.w = f2bf((o.w-mean)*rs*w.w);
    *reinterpret_cast<ushort4*>(&Ob[off]) = r;
}

// ---------------------------------------------------------------------------
extern "C" void kernel_launch(void* const* d_in, const int* in_sizes, int n_in,
                              void* d_out, int out_size, void* d_ws, size_t ws_size,
                              hipStream_t stream)
{
    const float* x     = (const float*)d_in[0];
    const float* W_in  = (const float*)d_in[1];
    const float* W_out = (const float*)d_in[2];
    const float* W_g1  = (const float*)d_in[3];
    const float* W_g2  = (const float*)d_in[4];
    const float* lnw   = (const float*)d_in[5];
    float* out = (float*)d_out;
    char* ws = (char*)d_ws;

    // workspace layout (bytes); total 246,415,360 (< 256 MiB)
    unsigned short* ub     = (unsigned short*)(ws);             // [B,N,3E] bf16 (dead after prep); reused:
    unsigned short* McTb   = (unsigned short*)(ws);             //   33,554,432
    unsigned short* Sb16   = (unsigned short*)(ws + 33554432);  //   33,554,432
    float*          EBC    = (float*)(ws + 100663296);          //       524,288
    unsigned short* QSb    = (unsigned short*)(ws + 101187584); //    16,777,216
    unsigned short* KINb   = (unsigned short*)(ws + 117964800); //    16,777,216
    unsigned short* KINtb  = (unsigned short*)(ws + 134742016); //    16,777,216
    unsigned short* Vtb    = (unsigned short*)(ws + 151519232); //    16,777,216
    float*          Opre   = (float*)(ws + 168296448);          //    33,554,432
    unsigned short* xb     = (unsigned short*)(ws + 201850880); //    16,777,216
    unsigned short* W_inb  = (unsigned short*)(ws + 218628096); //     6,291,456
    unsigned short* W_outb = (unsigned short*)(ws + 224919552); //     2,097,152
    unsigned short* W_g1b  = (unsigned short*)(ws + 227016704); //       262,144
    unsigned short* W_g2b  = (unsigned short*)(ws + 227278848); //       262,144
    unsigned short* G1b    = (unsigned short*)(ws + 227540992); //     2,097,152
    unsigned short* ObF    = (unsigned short*)(ws + 229638144); //    16,777,216
    unsigned short* G2b    = QSb;   // reuse QSb (dead after gla_output)

    const int M = B_*N_;     // 8192
    dim3 blk(256);

    // one merged cast launch
    cast_all<<<2048, blk, 0, stream>>>(x, W_in, W_out, W_g1, W_g2,
                                       xb, W_inb, W_outb, W_g1b, W_g2b);

    // 1) u = x @ W_in^T  (bf16 out) — pipelined 128x256 tile, counted vmcnt
    gemm_pipe<true><<<dim3(3*E_/256, M/128), dim3(512), 0, stream>>>(xb, W_inb, ub, M, 3*E_, E_);
    // 2) prep
    gla_prep<<<dim3(B_*H_*NC_), dim3(512), 0, stream>>>(ub, EBC, QSb, KINb, KINtb, Vtb);
    // 3) per-chunk summaries
    gla_chunk_mm<<<dim3(B_*H_*NC_), blk, 0, stream>>>(Vtb, KINtb, McTb);
    // 4) inter-chunk scan
    gla_scan_chunks<<<dim3((B_*H_*D_*D_)/256), blk, 0, stream>>>(McTb, EBC, Sb16);
    // 5) per-chunk outputs
    gla_output<<<dim3(B_*H_*NC_), blk, 0, stream>>>(QSb, KINb, Vtb, Sb16, Opre);
    // 6) G1 = x @ W_g1^T  (bf16 out)
    gemm_bf16<true><<<dim3(1, M/128), blk, 0, stream>>>(xb, W_g1b, G1b, M, D_, E_);
    // 7) G2 = G1 @ W_g2^T (bf16 out, over dead QSb)
    gemm_bf16<true><<<dim3(E_/128, M/128), blk, 0, stream>>>(G1b, W_g2b, G2b, M, E_, D_);
    // 8) gate + layernorm -> bf16
    gate_ln_bf16<<<dim3(M), blk, 0, stream>>>(Opre, G2b, lnw, ObF);
    // 9) out = LN(o) @ W_out^T — pipelined
    gemm_pipe<false><<<dim3(E_/256, M/128), dim3(512), 0, stream>>>(ObF, W_outb, out, M, E_, E_);
}

// Round 10
// 202.718 us; speedup vs baseline: 1.7306x; 1.0622x over previous
//
#include <hip/hip_runtime.h>
#include <cmath>

#define B_ 2
#define N_ 4096
#define E_ 1024
#define D_ 128
#define H_ 8
#define CHUNK 64
#define NC_ (N_/CHUNK)   // 64

__device__ __forceinline__ float sigmoidf_(float x){ return 1.f/(1.f + __expf(-x)); }

__device__ __forceinline__ unsigned short f2bf(float f){
    unsigned u = __float_as_uint(f);
    u += 0x7FFFu + ((u >> 16) & 1u);      // round-to-nearest-even
    return (unsigned short)(u >> 16);
}
__device__ __forceinline__ float bf2f(unsigned short s){
    return __uint_as_float(((unsigned)s) << 16);
}
__device__ __forceinline__ unsigned short f2bf_fast(float f){
    __bf16 h = (__bf16)f;
    return __builtin_bit_cast(unsigned short, h);
}

typedef __attribute__((ext_vector_type(8))) __bf16 bf16x8;
typedef __attribute__((ext_vector_type(4))) float  f32x4;
typedef __attribute__((address_space(3))) unsigned int as3_u32;
typedef __attribute__((address_space(1))) unsigned int as1_u32;

__device__ __forceinline__ void gload_lds16(const void* g, void* l){
    __builtin_amdgcn_global_load_lds((as1_u32*)g, (as3_u32*)l, 16, 0, 0);
}

__device__ __forceinline__ bf16x8 ldsfrag256(const unsigned short* Lp, int row, int kg){
    return *reinterpret_cast<const bf16x8*>(&Lp[row*128 + ((kg ^ (row&7))<<3)]);
}
__device__ __forceinline__ bf16x8 ldsfrag128(const unsigned short* Lp, int row, int kg){
    return *reinterpret_cast<const bf16x8*>(&Lp[row*64 + ((kg ^ (row&7))<<3)]);
}
__device__ __forceinline__ bf16x8 u4_to_bf(uint4 u){
    return __builtin_bit_cast(bf16x8, u);
}

// ---------------------------------------------------------------------------
// 128x128 bf16 MFMA GEMM (m97 structure, proven 59.5us @ step1).
// ---------------------------------------------------------------------------
template<bool OUT_BF16>
__global__ __launch_bounds__(256) void gemm_bf16(
    const unsigned short* __restrict__ A,
    const unsigned short* __restrict__ Bw,
    void* __restrict__ Cout, int M, int N, int K)
{
    __shared__ unsigned short As[128*64];
    __shared__ unsigned short Bs[128*64];
    const int tid  = threadIdx.x;
    const int wave = tid >> 6;
    const int lane = tid & 63;
    const int gx = gridDim.x;
    const int nwg = gx * gridDim.y;
    int bid = blockIdx.y*gx + blockIdx.x;
    bid = (bid & 7)*(nwg >> 3) + (bid >> 3);
    const int m0 = (bid / gx) * 128, n0 = (bid % gx) * 128;
    const int wr = (wave >> 1) * 64;
    const int wc = (wave & 1) * 64;
    const int l15 = lane & 15, l4 = lane >> 4;
    const int p = l15 & 7;

    f32x4 acc[4][4];
#pragma unroll
    for (int i=0;i<4;i++)
#pragma unroll
        for (int j=0;j<4;j++)
#pragma unroll
            for (int q=0;q<4;q++) acc[i][j][q]=0.f;

    const int srow = wave*32 + (lane>>3);
    const int sgrp = lane & 7;

    for (int k0=0; k0<K; k0+=64){
        if (k0) __syncthreads();
#pragma unroll
        for (int i=0;i<4;i++){
            const int r  = srow + 8*i;
            const int cg = sgrp ^ (r & 7);
            gload_lds16(A  + (size_t)(m0 + r)*K + k0 + cg*8, &As[(wave*32 + 8*i)*64]);
            gload_lds16(Bw + (size_t)(n0 + r)*K + k0 + cg*8, &Bs[(wave*32 + 8*i)*64]);
        }
        __syncthreads();
#pragma unroll
        for (int ks=0; ks<2; ks++){
            bf16x8 av[4], bv[4];
            const int tA = (((ks<<2) | l4) ^ p) << 3;
#pragma unroll
            for (int f=0; f<4; f++){
                const int rowA = wr + f*16 + l15;
                const int rowB = wc + f*16 + l15;
                av[f] = *reinterpret_cast<const bf16x8*>(&As[(rowA<<6) + tA]);
                bv[f] = *reinterpret_cast<const bf16x8*>(&Bs[(rowB<<6) + tA]);
            }
#pragma unroll
            for (int fm=0; fm<4; fm++)
#pragma unroll
                for (int fn=0; fn<4; fn++)
                    acc[fm][fn] = __builtin_amdgcn_mfma_f32_16x16x32_bf16(
                        av[fm], bv[fn], acc[fm][fn], 0, 0, 0);
        }
    }
    const int crow0 = m0 + wr + l4*4;
    const int ccol0 = n0 + wc + l15;
    if (!OUT_BF16){
        float* C = (float*)Cout;
#pragma unroll
        for (int fm=0; fm<4; fm++)
#pragma unroll
            for (int fn=0; fn<4; fn++)
#pragma unroll
                for (int j=0;j<4;j++)
                    C[(size_t)(crow0 + fm*16 + j)*N + ccol0 + fn*16] = acc[fm][fn][j];
    } else {
        unsigned short* C = (unsigned short*)Cout;
#pragma unroll
        for (int fm=0; fm<4; fm++)
#pragma unroll
            for (int fn=0; fn<4; fn++)
#pragma unroll
                for (int j=0;j<4;j++)
                    C[(size_t)(crow0 + fm*16 + j)*N + ccol0 + fn*16] = f2bf(acc[fm][fn][j]);
    }
}

// ---------------------------------------------------------------------------
// Merged f32 -> bf16 cast for all 5 inputs (one launch).
// ---------------------------------------------------------------------------
#define CQ0 2097152   // x quads
#define CQ1 786432    // W_in
#define CQ2 262144    // W_out
#define CQ3 32768     // W_g1
#define CQ4 32768     // W_g2
__global__ __launch_bounds__(256) void cast_all(
    const float* __restrict__ x,  const float* __restrict__ w1,
    const float* __restrict__ w2, const float* __restrict__ w3,
    const float* __restrict__ w4,
    unsigned short* __restrict__ xb,  unsigned short* __restrict__ w1b,
    unsigned short* __restrict__ w2b, unsigned short* __restrict__ w3b,
    unsigned short* __restrict__ w4b)
{
    const int total = CQ0+CQ1+CQ2+CQ3+CQ4;
    for (int i = blockIdx.x*256 + threadIdx.x; i < total; i += gridDim.x*256){
        const float* src; unsigned short* dst; int off;
        if (i < CQ0){ src=x; dst=xb; off=i; }
        else if (i < CQ0+CQ1){ src=w1; dst=w1b; off=i-CQ0; }
        else if (i < CQ0+CQ1+CQ2){ src=w2; dst=w2b; off=i-CQ0-CQ1; }
        else if (i < CQ0+CQ1+CQ2+CQ3){ src=w3; dst=w3b; off=i-CQ0-CQ1-CQ2; }
        else { src=w4; dst=w4b; off=i-CQ0-CQ1-CQ2-CQ3; }
        const float4 v = reinterpret_cast<const float4*>(src)[off];
        ushort4 o;
        o.x = f2bf(v.x); o.y = f2bf(v.y); o.z = f2bf(v.z); o.w = f2bf(v.w);
        reinterpret_cast<ushort4*>(dst)[off] = o;
    }
}

// ---------------------------------------------------------------------------
// Prep v4 (unchanged)
// ---------------------------------------------------------------------------
__global__ __launch_bounds__(512) void gla_prep(
    const unsigned short* __restrict__ u, float* __restrict__ EBC,
    unsigned short* __restrict__ QSb, unsigned short* __restrict__ KINb,
    unsigned short* __restrict__ KINtb, unsigned short* __restrict__ Vtb)
{
    __shared__ float tot[4*128];
    const int bid = blockIdx.x;               // (b*H+h)*NC + c
    const int c  = bid % NC_;
    const int hh = (bid / NC_) % H_;
    const int b  = bid / (NC_*H_);
    const int d  = threadIdx.x & 127;
    const int qd = threadIdx.x >> 7;
    const int t0 = qd*16;
    const size_t urow0 = ((size_t)b*N_ + (size_t)c*CHUNK)*(3*E_) + (size_t)hh*D_ + d;

    float bl[16], qv[16], vv[16];
#pragma unroll
    for (int i=0;i<16;i++)
        bl[i] = bf2f(u[urow0 + (size_t)(t0+i)*(3*E_) + 2*E_]);
#pragma unroll
    for (int i=0;i<16;i++)
        qv[i] = bf2f(u[urow0 + (size_t)(t0+i)*(3*E_) + E_]);
#pragma unroll
    for (int i=0;i<16;i++)
        vv[i] = bf2f(u[urow0 + (size_t)(t0+i)*(3*E_)]);

    float acc = 0.f;
#pragma unroll
    for (int i=0;i<16;i++){
        const float lg = bl[i];
        const float e  = __expf(-fabsf(lg));
        const float g  = fminf(lg, 0.f) - __logf(1.f + e);
        acc += g;
        bl[i] = acc;
    }
    tot[qd*128 + d] = acc;
    __syncthreads();
    const float s0 = tot[d], s1 = tot[128+d], s2 = tot[256+d], s3 = tot[384+d];
    const float off = (qd>0 ? s0 : 0.f) + (qd>1 ? s1 : 0.f) + (qd>2 ? s2 : 0.f);
    const float bcv = s0 + s1 + s2 + s3;
    const float ebc = __expf(bcv);
    if (threadIdx.x < 128) EBC[(size_t)bid*D_ + d] = ebc;

    unsigned kin_pk[8], v_pk[8];
    float prev = 0.f;
    const size_t obase = (size_t)bid*CHUNK*D_;
#pragma unroll
    for (int i=0;i<16;i++){
        const int t = t0 + i;
        const float Bl = bl[i];
        const float g  = Bl - prev;  prev = Bl;
        const float Bc = Bl + off;
        const float kk = 1.f - __expf(g);
        const float eB = __expf(Bc);
        const float q  = qv[i];
        const float es = __expf(-q);
        const float silu = q * __builtin_amdgcn_rcpf(1.f + es);
        const float qs  = silu * eB;
        const float kin = kk * __builtin_amdgcn_rcpf(eB);
        QSb [obase + (size_t)t*D_ + d] = f2bf_fast(qs);
        KINb[obase + (size_t)t*D_ + d] = f2bf_fast(kin);
        const unsigned kb = f2bf_fast(kin * ebc);
        const unsigned vb = f2bf_fast(vv[i]);
        if (i & 1){ kin_pk[i>>1] |= kb<<16; v_pk[i>>1] |= vb<<16; }
        else      { kin_pk[i>>1]  = kb;     v_pk[i>>1]  = vb;     }
    }
    const size_t tbase = (size_t)bid*D_*CHUNK + (size_t)d*CHUNK + t0;
#pragma unroll
    for (int j=0;j<2;j++){
        uint4 kq, vq;
        kq.x=kin_pk[4*j]; kq.y=kin_pk[4*j+1]; kq.z=kin_pk[4*j+2]; kq.w=kin_pk[4*j+3];
        vq.x=v_pk[4*j];   vq.y=v_pk[4*j+1];   vq.z=v_pk[4*j+2];   vq.w=v_pk[4*j+3];
        *reinterpret_cast<uint4*>(&KINtb[tbase + j*8]) = kq;
        *reinterpret_cast<uint4*>(&Vtb  [tbase + j*8]) = vq;
    }
}

// ---------------------------------------------------------------------------
__global__ __launch_bounds__(256) void gla_chunk_mm(
    const unsigned short* __restrict__ Vtb,
    const unsigned short* __restrict__ KINtb,
    unsigned short* __restrict__ McTb)
{
    __shared__ unsigned short As[128*64];
    __shared__ unsigned short Bs[128*64];
    const int bid = blockIdx.x;
    const int tid = threadIdx.x;
    const int w = tid >> 6, lane = tid & 63;
    const int l15 = lane & 15, l4 = lane >> 4;
    const int wr = (w >> 1) * 64, wc = (w & 1) * 64;
    const unsigned short* A  = Vtb   + (size_t)bid*128*64;
    const unsigned short* Bp = KINtb + (size_t)bid*128*64;

    f32x4 acc[4][4];
#pragma unroll
    for (int i=0;i<4;i++)
#pragma unroll
        for (int j=0;j<4;j++)
#pragma unroll
            for (int q=0;q<4;q++) acc[i][j][q]=0.f;

#pragma unroll
    for (int i=0;i<4;i++){
        const int r  = w*32 + i*8 + (lane>>3);
        const int gs = (lane&7) ^ (r&7);
        gload_lds16(A  + (size_t)r*64 + gs*8, &As[(w*32+i*8)*64]);
        gload_lds16(Bp + (size_t)r*64 + gs*8, &Bs[(w*32+i*8)*64]);
    }
    __syncthreads();
#pragma unroll
    for (int ks=0; ks<2; ks++){
        bf16x8 av[4], bv[4];
#pragma unroll
        for (int f=0; f<4; f++){
            av[f] = ldsfrag128(As, wr + f*16 + l15, ks*4 + l4);
            bv[f] = ldsfrag128(Bs, wc + f*16 + l15, ks*4 + l4);
        }
#pragma unroll
        for (int fm=0; fm<4; fm++)
#pragma unroll
            for (int fn=0; fn<4; fn++)
                acc[fm][fn] = __builtin_amdgcn_mfma_f32_16x16x32_bf16(
                    av[fm], bv[fn], acc[fm][fn], 0, 0, 0);
    }
    unsigned short* C = McTb + (size_t)bid*128*128;
#pragma unroll
    for (int fm=0; fm<4; fm++)
#pragma unroll
        for (int fn=0; fn<4; fn++)
#pragma unroll
            for (int j=0;j<4;j++)
                C[(size_t)(wr + fm*16 + l4*4 + j)*128 + wc + fn*16 + l15] = f2bf(acc[fm][fn][j]);
}

// ---------------------------------------------------------------------------
__global__ __launch_bounds__(256) void gla_scan_chunks(
    const unsigned short* __restrict__ McTb, const float* __restrict__ EBC,
    unsigned short* __restrict__ Sb16)
{
    const size_t F = (size_t)blockIdx.x*256 + threadIdx.x;   // < B*H*D*D
    const int bh = (int)(F >> 14);
    const int rem = (int)(F & 16383);
    const int d = rem & 127;
    float S = 0.f;
    for (int c=0;c<NC_;c++){
        const size_t idx = (((size_t)bh*NC_ + c) << 14) + rem;
        const float m = bf2f(McTb[idx]);
        const float dec = EBC[((size_t)bh*NC_ + c)*D_ + d];
        Sb16[idx] = f2bf(S);
        S = dec*S + m;
    }
}

// ---------------------------------------------------------------------------
// Output v2: LDS only for QS (2x reuse, 16KB) + A-handoff (8KB) -> ~3 blk/CU.
// KIN/Vt/S fragments loaded DIRECT from global (zero intra-block reuse).
// Gate fused into epilogue; Opre written as bf16.
// ---------------------------------------------------------------------------
__global__ __launch_bounds__(256) void gla_output(
    const unsigned short* __restrict__ QSb,
    const unsigned short* __restrict__ KINb,
    const unsigned short* __restrict__ Vtb,
    const unsigned short* __restrict__ Sb,
    const unsigned short* __restrict__ G2b,
    unsigned short* __restrict__ Opre)
{
    __shared__ unsigned short QS_l[64*128];   // 16 KB
    __shared__ unsigned short A_l [64*64];    //  8 KB
    const int bid = blockIdx.x;
    const int c = bid % NC_;
    const int h = (bid / NC_) % H_;
    const int b = bid / (NC_*H_);
    const int tid = threadIdx.x;
    const int w = tid >> 6, lane = tid & 63;
    const int l15 = lane & 15, l4 = lane >> 4;

    const unsigned short* qb = QSb + (size_t)bid*64*128;
    const unsigned short* kb = KINb + (size_t)bid*64*128;
    const unsigned short* vb = Vtb + (size_t)bid*128*64;
    const unsigned short* sb = Sb  + (size_t)bid*128*128;

    // stage QS into LDS (pre-swizzled source, linear dest)
#pragma unroll
    for (int i=0;i<4;i++){
        const int r  = w*16 + i*4 + (lane>>4);
        const int gs = (lane&15) ^ (r&7);
        gload_lds16(qb + (size_t)r*128 + gs*8, &QS_l[(w*16+i*4)*128]);
    }
    // direct KIN fragment loads (needed in phase A; drained by sync1)
    uint4 kinr[4];
    {
        const int srow = w*16 + l15;
#pragma unroll
        for (int ks=0; ks<4; ks++)
            kinr[ks] = *reinterpret_cast<const uint4*>(kb + (size_t)srow*128 + (ks*4 + l4)*8);
    }
    __syncthreads();   // drains gload_lds + kinr

    // issue Vt/S direct loads now -> overlap phase A (T14)
    uint4 vtr[2][2], sr[2][4];
#pragma unroll
    for (int fe=0; fe<2; fe++){
        const int row = w*32 + fe*16 + l15;
#pragma unroll
        for (int ks=0; ks<2; ks++)
            vtr[fe][ks] = *reinterpret_cast<const uint4*>(vb + (size_t)row*64 + (ks*4 + l4)*8);
#pragma unroll
        for (int ks=0; ks<4; ks++)
            sr[fe][ks]  = *reinterpret_cast<const uint4*>(sb + (size_t)row*128 + (ks*4 + l4)*8);
    }

    // ---- phase A: A[t, w*16+l15] = sum_d QS[t,d] KIN[s,d] ----
    f32x4 accA[4];
#pragma unroll
    for (int i=0;i<4;i++)
#pragma unroll
        for (int q=0;q<4;q++) accA[i][q]=0.f;
#pragma unroll
    for (int ks=0; ks<4; ks++){
        const bf16x8 bv = u4_to_bf(kinr[ks]);
#pragma unroll
        for (int ft=0; ft<4; ft++){
            const bf16x8 av = ldsfrag256(QS_l, ft*16 + l15, ks*4 + l4);
            accA[ft] = __builtin_amdgcn_mfma_f32_16x16x32_bf16(av, bv, accA[ft], 0,0,0);
        }
    }
    // write masked bf16 A into A_l (swizzled)
#pragma unroll
    for (int ft=0; ft<4; ft++)
#pragma unroll
        for (int j=0;j<4;j++){
            const int t = ft*16 + l4*4 + j;
            const int s = w*16 + l15;
            const float vA = (t >= s) ? accA[ft][j] : 0.f;
            A_l[t*64 + (((s>>3) ^ (t&7))<<3) + (s&7)] = f2bf(vA);
        }
    __syncthreads();   // A visible to all waves; drains vtr/sr

    // ---- phase B: O = A @ Vt^T + QS @ S^T ----
    f32x4 acc[4][2];
#pragma unroll
    for (int i=0;i<4;i++)
#pragma unroll
        for (int j=0;j<2;j++)
#pragma unroll
            for (int q=0;q<4;q++) acc[i][j][q]=0.f;
#pragma unroll
    for (int ks=0; ks<2; ks++){                 // O1: K = s = 64
        const bf16x8 b0 = u4_to_bf(vtr[0][ks]);
        const bf16x8 b1 = u4_to_bf(vtr[1][ks]);
#pragma unroll
        for (int ft=0; ft<4; ft++){
            const bf16x8 av = ldsfrag128(A_l, ft*16 + l15, ks*4 + l4);
            acc[ft][0] = __builtin_amdgcn_mfma_f32_16x16x32_bf16(av, b0, acc[ft][0], 0,0,0);
            acc[ft][1] = __builtin_amdgcn_mfma_f32_16x16x32_bf16(av, b1, acc[ft][1], 0,0,0);
        }
    }
#pragma unroll
    for (int ks=0; ks<4; ks++){                 // O2: K = d = 128
        const bf16x8 b0 = u4_to_bf(sr[0][ks]);
        const bf16x8 b1 = u4_to_bf(sr[1][ks]);
#pragma unroll
        for (int ft=0; ft<4; ft++){
            const bf16x8 av = ldsfrag256(QS_l, ft*16 + l15, ks*4 + l4);
            acc[ft][0] = __builtin_amdgcn_mfma_f32_16x16x32_bf16(av, b0, acc[ft][0], 0,0,0);
            acc[ft][1] = __builtin_amdgcn_mfma_f32_16x16x32_bf16(av, b1, acc[ft][1], 0,0,0);
        }
    }
    // epilogue: gate (sigmoid of G2) + bf16 store into [B,N,E]
    const size_t rowbase = (size_t)b*N_ + (size_t)c*CHUNK;
#pragma unroll
    for (int ft=0; ft<4; ft++)
#pragma unroll
        for (int fe=0; fe<2; fe++)
#pragma unroll
            for (int j=0;j<4;j++){
                const int t = ft*16 + l4*4 + j;
                const int e = w*32 + fe*16 + l15;
                const size_t idx = (rowbase + t)*E_ + h*D_ + e;
                const float g = sigmoidf_(bf2f(G2b[idx]));
                Opre[idx] = f2bf(acc[ft][fe][j] * g);
            }
}

// ---------------------------------------------------------------------------
// LayerNorm (gate already applied) : bf16 in -> bf16 out
// ---------------------------------------------------------------------------
__global__ __launch_bounds__(256) void ln_bf16(
    const unsigned short* __restrict__ O, const float* __restrict__ lnw,
    unsigned short* __restrict__ Ob)
{
    const int row = blockIdx.x;
    const int tid = threadIdx.x;
    const size_t off = (size_t)row*E_ + tid*4;
    const ushort4 ov = *reinterpret_cast<const ushort4*>(&O[off]);
    float4 o;
    o.x = bf2f(ov.x); o.y = bf2f(ov.y); o.z = bf2f(ov.z); o.w = bf2f(ov.w);
    float s1 = o.x+o.y+o.z+o.w;
    float s2 = o.x*o.x + o.y*o.y + o.z*o.z + o.w*o.w;
#pragma unroll
    for (int sh=32; sh>0; sh>>=1){
        s1 += __shfl_down(s1, sh);
        s2 += __shfl_down(s2, sh);
    }
    __shared__ float r1[4], r2[4];
    const int wid = tid >> 6;
    if ((tid & 63)==0){ r1[wid]=s1; r2[wid]=s2; }
    __syncthreads();
    s1 = r1[0]+r1[1]+r1[2]+r1[3];
    s2 = r2[0]+r2[1]+r2[2]+r2[3];
    const float mean = s1 * (1.f/E_);
    const float var  = s2 * (1.f/E_) - mean*mean;
    const float rs   = rsqrtf(var + 1e-5f);
    const float4 w = *reinterpret_cast<const float4*>(&lnw[tid*4]);
    ushort4 r;
    r.x = f2bf((o.x-mean)*rs*w.x); r.y = f2bf((o.y-mean)*rs*w.y);
    r.z = f2bf((o.z-mean)*rs*w.z); r.w = f2bf((o.w-mean)*rs*w.w);
    *reinterpret_cast<ushort4*>(&Ob[off]) = r;
}

// ---------------------------------------------------------------------------
extern "C" void kernel_launch(void* const* d_in, const int* in_sizes, int n_in,
                              void* d_out, int out_size, void* d_ws, size_t ws_size,
                              hipStream_t stream)
{
    const float* x     = (const float*)d_in[0];
    const float* W_in  = (const float*)d_in[1];
    const float* W_out = (const float*)d_in[2];
    const float* W_g1  = (const float*)d_in[3];
    const float* W_g2  = (const float*)d_in[4];
    const float* lnw   = (const float*)d_in[5];
    float* out = (float*)d_out;
    char* ws = (char*)d_ws;

    // workspace layout (bytes); total 246,415,360 (< 256 MiB)
    unsigned short* ub     = (unsigned short*)(ws);             // [B,N,3E] bf16 (dead after prep); reused:
    unsigned short* McTb   = (unsigned short*)(ws);             //   33,554,432
    unsigned short* Sb16   = (unsigned short*)(ws + 33554432);  //   33,554,432
    unsigned short* G2b    = (unsigned short*)(ws + 67108864);  //   16,777,216 (fresh; written before gla_output)
    float*          EBC    = (float*)(ws + 100663296);          //       524,288
    unsigned short* QSb    = (unsigned short*)(ws + 101187584); //    16,777,216
    unsigned short* KINb   = (unsigned short*)(ws + 117964800); //    16,777,216
    unsigned short* KINtb  = (unsigned short*)(ws + 134742016); //    16,777,216
    unsigned short* Vtb    = (unsigned short*)(ws + 151519232); //    16,777,216
    unsigned short* Opre   = (unsigned short*)(ws + 168296448); //    16,777,216 (bf16 now)
    unsigned short* xb     = (unsigned short*)(ws + 201850880); //    16,777,216
    unsigned short* W_inb  = (unsigned short*)(ws + 218628096); //     6,291,456
    unsigned short* W_outb = (unsigned short*)(ws + 224919552); //     2,097,152
    unsigned short* W_g1b  = (unsigned short*)(ws + 227016704); //       262,144
    unsigned short* W_g2b  = (unsigned short*)(ws + 227278848); //       262,144
    unsigned short* G1b    = (unsigned short*)(ws + 227540992); //     2,097,152
    unsigned short* ObF    = (unsigned short*)(ws + 229638144); //    16,777,216

    const int M = B_*N_;     // 8192
    dim3 blk(256);

    // one merged cast launch
    cast_all<<<2048, blk, 0, stream>>>(x, W_in, W_out, W_g1, W_g2,
                                       xb, W_inb, W_outb, W_g1b, W_g2b);

    // 1) u = x @ W_in^T  (bf16 out) — m97 128^2 (proven)
    gemm_bf16<true><<<dim3(3*E_/128, M/128), blk, 0, stream>>>(xb, W_inb, ub, M, 3*E_, E_);
    // 2) prep
    gla_prep<<<dim3(B_*H_*NC_), dim3(512), 0, stream>>>(ub, EBC, QSb, KINb, KINtb, Vtb);
    // 3) per-chunk summaries
    gla_chunk_mm<<<dim3(B_*H_*NC_), blk, 0, stream>>>(Vtb, KINtb, McTb);
    // 4) inter-chunk scan
    gla_scan_chunks<<<dim3((B_*H_*D_*D_)/256), blk, 0, stream>>>(McTb, EBC, Sb16);
    // 5) low-rank gate: G1 = x @ W_g1^T ; G2 = G1 @ W_g2^T (before gla_output)
    gemm_bf16<true><<<dim3(1, M/128), blk, 0, stream>>>(xb, W_g1b, G1b, M, D_, E_);
    gemm_bf16<true><<<dim3(E_/128, M/128), blk, 0, stream>>>(G1b, W_g2b, G2b, M, E_, D_);
    // 6) per-chunk outputs + fused gate -> bf16 Opre
    gla_output<<<dim3(B_*H_*NC_), blk, 0, stream>>>(QSb, KINb, Vtb, Sb16, G2b, Opre);
    // 7) layernorm -> bf16
    ln_bf16<<<dim3(M), blk, 0, stream>>>(Opre, lnw, ObF);
    // 8) out = LN(o) @ W_out^T
    gemm_bf16<false><<<dim3(E_/128, M/128), blk, 0, stream>>>(ObF, W_outb, out, M, E_, E_);
}